// Round 6
// baseline (175.060 us; speedup 1.0000x reference)
//
#include <hip/hip_runtime.h>
#include <hip/hip_bf16.h>

// Problem dims (fixed): B=2, N=1024, SR=1, S=seq_in*nh_in=64, NV=4, NC=32,
// NLON=NLAT=4 -> NJ=16 basis pairs. NWIN = B*N = 2048.
#define NWIN 2048
#define SDIM 64
#define NJ 16

__device__ __forceinline__ float bf2f(unsigned int u16) {
    union { unsigned int i; float f; } v;
    v.i = u16 << 16;
    return v.f;
}

// R6: one window per BLOCK, wave = (window, v) -> 8192 waves (4x R3's TLP).
// lane = (sg = lane>>3: s-group, c4 = lane&7: 4-channel group).
// Each lane: 8 independent 8B uint2 loads (4 bf16 ch), s = 8*it + sg.
// acc[16][4], COMPILE-TIME indices only -- R4/R5's epilogues indexed acc[]
// with runtime j (half*8+j2 / sp*4+jj), which lowers reg-arrays to scratch
// (R4: VGPR_Count=64 yet WRITE 83MB vs 17MB ideal = scratch streaming).
// 3-level shfl_xor(8,16,32) s-reduction; sg==0 lanes store 16x float4
// (static j loop; 128B contiguous per j). Normalizer folded as 1/S[j].
//
// Dtypes (R1-R5 evidence): x bf16 (FETCH~35MB), coords/params/out f32.
// Probes retained so a dtype flip cannot break correctness.
__global__ __launch_bounds__(256, 4) void gauss_agg_kernel(
    const void* __restrict__ x,       // (NWIN, S, NV=4, NC=32)
    const void* __restrict__ clon,    // (NWIN, S)
    const void* __restrict__ clat,    // (NWIN, S)
    const void* __restrict__ mlon,    // (4)
    const void* __restrict__ mlat,    // (4)
    const void* __restrict__ sigma,   // (1)
    float* __restrict__ out)          // (NWIN, NV, NJ, NC) f32
{
    __shared__ alignas(16) float s_wlon[SDIM][4];
    __shared__ alignas(16) float s_wlat[SDIM][4];
    __shared__ float s_sinv[NJ];
    __shared__ int s_flags;

    const int tid = threadIdx.x;
    const int win = blockIdx.x;

    // ---------------- dtype probes (uniform) ----------------
    if (tid == 0) {
        const unsigned short* px = (const unsigned short*)x;
        const unsigned short* pc = (const unsigned short*)clon;
        int vx = 0, vc = 0;
#pragma unroll
        for (int i = 0; i < 16; ++i) {
            const int ex = (px[2 * i] >> 7) & 0xFF;
            vx += (ex >= 102 && ex <= 134);
            const int ec = (pc[2 * i] >> 7) & 0xFF;
            vc += (ec >= 102 && ec <= 134);
        }
        int f = 0;
        if (vx >= 12) f |= 1;                                   // x is bf16
        if (vc >= 12) f |= 2;                                   // coords bf16
        if (((const unsigned short*)mlon)[0] != 0) f |= 4;      // mus bf16
        if (((const unsigned short*)sigma)[0] != 0) f |= 8;     // sigma bf16
        s_flags = f;
    }
    __syncthreads();
    const int flags = s_flags;
    const bool xb = flags & 1, cb = flags & 2, mb = flags & 4, sb = flags & 8;

    // ---------------- phase 1: weights (wave 0, lane == s) ----------------
    if (tid < 64) {
        const int lane = tid;
        const float sigraw = sb ? bf2f(((const unsigned short*)sigma)[0])
                                : ((const float*)sigma)[0];
        const float inv = 1.0f / fmaxf(sigraw, 1e-10f);

        float mlo[4], mla[4];
#pragma unroll
        for (int l = 0; l < 4; ++l) {
            mlo[l] = mb ? bf2f(((const unsigned short*)mlon)[l])
                        : ((const float*)mlon)[l];
            mla[l] = mb ? bf2f(((const unsigned short*)mlat)[l])
                        : ((const float*)mlat)[l];
        }

        float lon, lat;
        if (cb) {
            lon = bf2f(((const unsigned short*)clon)[win * SDIM + lane]);
            lat = bf2f(((const unsigned short*)clat)[win * SDIM + lane]);
        } else {
            lon = ((const float*)clon)[win * SDIM + lane];
            lat = ((const float*)clat)[win * SDIM + lane];
        }

        float wlon[4], wlat[4];
#pragma unroll
        for (int l = 0; l < 4; ++l) {
            const float dlo = (lon - mlo[l]) * inv;
            wlon[l] = __expf(-0.5f * dlo * dlo);
            const float dla = (lat - mla[l]) * inv;
            wlat[l] = __expf(-0.5f * dla * dla);
        }
        *reinterpret_cast<float4*>(&s_wlon[lane][0]) =
            make_float4(wlon[0], wlon[1], wlon[2], wlon[3]);
        *reinterpret_cast<float4*>(&s_wlat[lane][0]) =
            make_float4(wlat[0], wlat[1], wlat[2], wlat[3]);

        // normalizer S[j] via wave butterfly over s
        float p[NJ];
#pragma unroll
        for (int lo = 0; lo < 4; ++lo)
#pragma unroll
            for (int la = 0; la < 4; ++la)
                p[lo * 4 + la] = wlon[lo] * wlat[la];
#pragma unroll
        for (int j = 0; j < NJ; ++j) {
            float v = p[j];
#pragma unroll
            for (int off = 1; off < 64; off <<= 1)
                v += __shfl_xor(v, off, 64);
            p[j] = v;
        }
        if (lane == 0) {
#pragma unroll
            for (int j = 0; j < NJ; ++j)
                s_sinv[j] = 1.0f / p[j];
        }
    }
    __syncthreads();

    // ---------------- phase 2: aggregation (wave = v) ----------------
    const int v    = tid >> 6;      // variable 0..3 (one per wave)
    const int lane = tid & 63;
    const int sg   = lane >> 3;     // s-group 0..7: s = 8*it + sg
    const int c4   = lane & 7;      // channels 4*c4 .. 4*c4+3

    const float4* wl4 = reinterpret_cast<const float4*>(&s_wlon[0][0]);
    const float4* wt4 = reinterpret_cast<const float4*>(&s_wlat[0][0]);

    float acc[NJ][4];
#pragma unroll
    for (int j = 0; j < NJ; ++j)
#pragma unroll
        for (int k = 0; k < 4; ++k) acc[j][k] = 0.0f;

    // 4-channel-group units: index = win*2048 + s*32 + v*8 + c4
    //   bf16: uint2 (4 x bf16);  f32: float4 (4 x f32) -- same unit count.
    const size_t base = (size_t)win * 2048 + v * 8 + c4;

    if (xb) {
        const uint2* xp = (const uint2*)x + base;
#pragma unroll
        for (int it = 0; it < 8; ++it) {
            const int s = 8 * it + sg;
            const uint2 u = xp[(size_t)s * 32];
            union { unsigned int i; float fl; } a0, a1, a2, a3;
            a0.i = u.x << 16; a1.i = u.x & 0xffff0000u;
            a2.i = u.y << 16; a3.i = u.y & 0xffff0000u;
            const float f[4] = { a0.fl, a1.fl, a2.fl, a3.fl };
            const float4 wl = wl4[s];
            const float4 wt = wt4[s];
            const float wlv[4] = { wl.x, wl.y, wl.z, wl.w };
            const float wtv[4] = { wt.x, wt.y, wt.z, wt.w };
            float t[4][4];
#pragma unroll
            for (int la = 0; la < 4; ++la)
#pragma unroll
                for (int k = 0; k < 4; ++k) t[la][k] = f[k] * wtv[la];
#pragma unroll
            for (int lo = 0; lo < 4; ++lo)
#pragma unroll
                for (int la = 0; la < 4; ++la)
#pragma unroll
                    for (int k = 0; k < 4; ++k)
                        acc[lo * 4 + la][k] += wlv[lo] * t[la][k];
        }
    } else {
        const float4* xp = (const float4*)x + base;
#pragma unroll
        for (int it = 0; it < 8; ++it) {
            const int s = 8 * it + sg;
            const float4 xv = xp[(size_t)s * 32];
            const float f[4] = { xv.x, xv.y, xv.z, xv.w };
            const float4 wl = wl4[s];
            const float4 wt = wt4[s];
            const float wlv[4] = { wl.x, wl.y, wl.z, wl.w };
            const float wtv[4] = { wt.x, wt.y, wt.z, wt.w };
            float t[4][4];
#pragma unroll
            for (int la = 0; la < 4; ++la)
#pragma unroll
                for (int k = 0; k < 4; ++k) t[la][k] = f[k] * wtv[la];
#pragma unroll
            for (int lo = 0; lo < 4; ++lo)
#pragma unroll
                for (int la = 0; la < 4; ++la)
#pragma unroll
                    for (int k = 0; k < 4; ++k)
                        acc[lo * 4 + la][k] += wlv[lo] * t[la][k];
        }
    }

    // s-reduction over sg (lane bits 3,4,5) -- all indices compile-time
#pragma unroll
    for (int j = 0; j < NJ; ++j)
#pragma unroll
        for (int k = 0; k < 4; ++k) {
            float t = acc[j][k];
            t += __shfl_xor(t, 8, 64);
            t += __shfl_xor(t, 16, 64);
            t += __shfl_xor(t, 32, 64);
            acc[j][k] = t;
        }

    // ---------------- epilogue: normalize, store f32 ----------------
    // sg==0 lanes (8 per wave) store all 16 j as float4; j loop is STATIC.
    if (sg == 0) {
        float4* op = reinterpret_cast<float4*>(out);
#pragma unroll
        for (int j = 0; j < NJ; ++j) {
            const float si = s_sinv[j];
            // out float4 index = ((win*4 + v)*16 + j)*8 + c4
            op[((size_t)(win * 4 + v) * NJ + j) * 8 + c4] =
                make_float4(acc[j][0] * si, acc[j][1] * si,
                            acc[j][2] * si, acc[j][3] * si);
        }
    }
}

extern "C" void kernel_launch(void* const* d_in, const int* in_sizes, int n_in,
                              void* d_out, int out_size, void* d_ws, size_t ws_size,
                              hipStream_t stream) {
    dim3 grid(NWIN);       // one window per block, 4 v-waves per block
    dim3 block(256);
    gauss_agg_kernel<<<grid, block, 0, stream>>>(
        d_in[0], d_in[1], d_in[2], d_in[3], d_in[4], d_in[5],
        (float*)d_out);
}

// Round 7
// 115.045 us; speedup vs baseline: 1.5217x; 1.5217x over previous
//
#include <hip/hip_runtime.h>
#include <hip/hip_bf16.h>

// Problem dims (fixed): B=2, N=1024, SR=1, S=seq_in*nh_in=64, NV=4, NC=32,
// NLON=NLAT=4 -> NJ=16 basis pairs. NWIN = B*N = 2048.
#define NWIN 2048
#define SDIM 64
#define NJ 16

__device__ __forceinline__ float bf2f(unsigned int u16) {
    union { unsigned int i; float f; } v;
    v.i = u16 << 16;
    return v.f;
}

// R7. Hard-won spill model (R3-R6 counters):
//   - the allocator targets 64 VGPRs (8 waves/EU) and SPILLS TO SCRATCH
//     rather than trade occupancy (R6: VGPR_Count=64, WRITE 166MB vs 17MB
//     ideal with a 64-float acc; R4 identical at launch_bounds min=2);
//   - ANY runtime index into a register array kills SROA -> whole array in
//     scratch (R4/R5 epilogues).
// Invariant: per-thread arrays <= 32 floats, compile-time indices ONLY.
//
// Structure: one window per BLOCK, wave = (window, v) -> 8192 waves (4x R3).
// lane = (sh = lane>>4: s-phase 0..3, c2 = lane&15: channel pair).
// Main loop: 16 iters of 4B loads (s = 4*it+sh), acc[16][2] (R3's proven
// no-spill budget). shfl_xor(16,32) s-reduction (static unrolled). Epilogue:
// sh==0 lanes store all 16 j in a STATIC loop, 128B contiguous per j.
// Normalizer folded to epilogue as 1/S[j].
//
// Dtypes (R1-R6 evidence): x bf16 (FETCH~35MB), coords/params/out f32.
// Probes retained (one thread, negligible) so a dtype flip cannot break us.
__global__ __launch_bounds__(256, 4) void gauss_agg_kernel(
    const void* __restrict__ x,       // (NWIN, S, NV=4, NC=32)
    const void* __restrict__ clon,    // (NWIN, S)
    const void* __restrict__ clat,    // (NWIN, S)
    const void* __restrict__ mlon,    // (4)
    const void* __restrict__ mlat,    // (4)
    const void* __restrict__ sigma,   // (1)
    float* __restrict__ out)          // (NWIN, NV, NJ, NC) f32
{
    __shared__ alignas(16) float s_wlon[SDIM][4];
    __shared__ alignas(16) float s_wlat[SDIM][4];
    __shared__ float s_sinv[NJ];
    __shared__ int s_flags;

    const int tid = threadIdx.x;
    const int win = blockIdx.x;

    // ---------------- dtype probes (uniform) ----------------
    if (tid == 0) {
        const unsigned short* px = (const unsigned short*)x;
        const unsigned short* pc = (const unsigned short*)clon;
        int vx = 0, vc = 0;
#pragma unroll
        for (int i = 0; i < 16; ++i) {
            const int ex = (px[2 * i] >> 7) & 0xFF;
            vx += (ex >= 102 && ex <= 134);
            const int ec = (pc[2 * i] >> 7) & 0xFF;
            vc += (ec >= 102 && ec <= 134);
        }
        int f = 0;
        if (vx >= 12) f |= 1;                                   // x is bf16
        if (vc >= 12) f |= 2;                                   // coords bf16
        if (((const unsigned short*)mlon)[0] != 0) f |= 4;      // mus bf16
        if (((const unsigned short*)sigma)[0] != 0) f |= 8;     // sigma bf16
        s_flags = f;
    }
    __syncthreads();
    const int flags = s_flags;
    const bool xb = flags & 1, cb = flags & 2, mb = flags & 4, sb = flags & 8;

    // ---------------- phase 1: weights (wave 0, lane == s) ----------------
    if (tid < 64) {
        const int lane = tid;
        const float sigraw = sb ? bf2f(((const unsigned short*)sigma)[0])
                                : ((const float*)sigma)[0];
        const float inv = 1.0f / fmaxf(sigraw, 1e-10f);

        float mlo[4], mla[4];
#pragma unroll
        for (int l = 0; l < 4; ++l) {
            mlo[l] = mb ? bf2f(((const unsigned short*)mlon)[l])
                        : ((const float*)mlon)[l];
            mla[l] = mb ? bf2f(((const unsigned short*)mlat)[l])
                        : ((const float*)mlat)[l];
        }

        float lon, lat;
        if (cb) {
            lon = bf2f(((const unsigned short*)clon)[win * SDIM + lane]);
            lat = bf2f(((const unsigned short*)clat)[win * SDIM + lane]);
        } else {
            lon = ((const float*)clon)[win * SDIM + lane];
            lat = ((const float*)clat)[win * SDIM + lane];
        }

        float wlon[4], wlat[4];
#pragma unroll
        for (int l = 0; l < 4; ++l) {
            const float dlo = (lon - mlo[l]) * inv;
            wlon[l] = __expf(-0.5f * dlo * dlo);
            const float dla = (lat - mla[l]) * inv;
            wlat[l] = __expf(-0.5f * dla * dla);
        }
        *reinterpret_cast<float4*>(&s_wlon[lane][0]) =
            make_float4(wlon[0], wlon[1], wlon[2], wlon[3]);
        *reinterpret_cast<float4*>(&s_wlat[lane][0]) =
            make_float4(wlat[0], wlat[1], wlat[2], wlat[3]);

        // normalizer S[j] via wave butterfly over s (static indices)
        float p[NJ];
#pragma unroll
        for (int lo = 0; lo < 4; ++lo)
#pragma unroll
            for (int la = 0; la < 4; ++la)
                p[lo * 4 + la] = wlon[lo] * wlat[la];
#pragma unroll
        for (int j = 0; j < NJ; ++j) {
            float v = p[j];
#pragma unroll
            for (int off = 1; off < 64; off <<= 1)
                v += __shfl_xor(v, off, 64);
            p[j] = v;
        }
        if (lane == 0) {
#pragma unroll
            for (int j = 0; j < NJ; ++j)
                s_sinv[j] = 1.0f / p[j];
        }
    }
    __syncthreads();

    // ---------------- phase 2: aggregation (wave = v) ----------------
    const int v    = tid >> 6;      // variable 0..3 (one per wave)
    const int lane = tid & 63;
    const int sh   = lane >> 4;     // s-phase 0..3: s = 4*it + sh
    const int c2   = lane & 15;     // channel pair (c = 2*c2, 2*c2+1)

    const float4* wl4 = reinterpret_cast<const float4*>(&s_wlon[0][0]);
    const float4* wt4 = reinterpret_cast<const float4*>(&s_wlat[0][0]);

    float acc0[NJ], acc1[NJ];
#pragma unroll
    for (int j = 0; j < NJ; ++j) { acc0[j] = 0.0f; acc1[j] = 0.0f; }

    // 2-channel units: index = win*4096 + s*64 + v*16 + c2
    //   bf16: uint (2 x bf16);  f32: float2 (2 x f32) -- same unit count.
    const size_t base = (size_t)win * 4096 + v * 16 + c2;

    if (xb) {
        const unsigned int* xp = (const unsigned int*)x + base;
#pragma unroll 4
        for (int it = 0; it < 16; ++it) {
            const int s = 4 * it + sh;
            const unsigned int u = xp[(size_t)s * 64];
            union { unsigned int i; float fl; } u0, u1;
            u0.i = u << 16;
            u1.i = u & 0xffff0000u;
            const float f0 = u0.fl, f1 = u1.fl;
            const float4 wl = wl4[s];
            const float4 wt = wt4[s];
            const float wlv[4] = { wl.x, wl.y, wl.z, wl.w };
            const float wtv[4] = { wt.x, wt.y, wt.z, wt.w };
            float t0[4], t1[4];
#pragma unroll
            for (int la = 0; la < 4; ++la) { t0[la] = f0 * wtv[la]; t1[la] = f1 * wtv[la]; }
#pragma unroll
            for (int lo = 0; lo < 4; ++lo)
#pragma unroll
                for (int la = 0; la < 4; ++la) {
                    acc0[lo * 4 + la] += wlv[lo] * t0[la];
                    acc1[lo * 4 + la] += wlv[lo] * t1[la];
                }
        }
    } else {
        const float2* xp = (const float2*)x + base;
#pragma unroll 4
        for (int it = 0; it < 16; ++it) {
            const int s = 4 * it + sh;
            const float2 xv = xp[(size_t)s * 64];
            const float f0 = xv.x, f1 = xv.y;
            const float4 wl = wl4[s];
            const float4 wt = wt4[s];
            const float wlv[4] = { wl.x, wl.y, wl.z, wl.w };
            const float wtv[4] = { wt.x, wt.y, wt.z, wt.w };
            float t0[4], t1[4];
#pragma unroll
            for (int la = 0; la < 4; ++la) { t0[la] = f0 * wtv[la]; t1[la] = f1 * wtv[la]; }
#pragma unroll
            for (int lo = 0; lo < 4; ++lo)
#pragma unroll
                for (int la = 0; la < 4; ++la) {
                    acc0[lo * 4 + la] += wlv[lo] * t0[la];
                    acc1[lo * 4 + la] += wlv[lo] * t1[la];
                }
        }
    }

    // s-reduction over sh (lane bits 4,5) -- static indices only
#pragma unroll
    for (int j = 0; j < NJ; ++j) {
        float a = acc0[j], b = acc1[j];
        a += __shfl_xor(a, 16, 64);
        a += __shfl_xor(a, 32, 64);
        b += __shfl_xor(b, 16, 64);
        b += __shfl_xor(b, 32, 64);
        acc0[j] = a; acc1[j] = b;
    }

    // ---------------- epilogue: normalize, store f32 ----------------
    // sh==0 lanes (16 per wave) store all 16 j; j loop is STATIC.
    // Per j: 16 lanes x float2 = 128 B contiguous.
    if (sh == 0) {
        float2* op = reinterpret_cast<float2*>(out);
#pragma unroll
        for (int j = 0; j < NJ; ++j) {
            const float si = s_sinv[j];
            // out float2 index = ((win*4 + v)*16 + j)*16 + c2
            op[((size_t)(win * 4 + v) * NJ + j) * 16 + c2] =
                make_float2(acc0[j] * si, acc1[j] * si);
        }
    }
}

extern "C" void kernel_launch(void* const* d_in, const int* in_sizes, int n_in,
                              void* d_out, int out_size, void* d_ws, size_t ws_size,
                              hipStream_t stream) {
    dim3 grid(NWIN);       // one window per block, 4 v-waves per block
    dim3 block(256);
    gauss_agg_kernel<<<grid, block, 0, stream>>>(
        d_in[0], d_in[1], d_in[2], d_in[3], d_in[4], d_in[5],
        (float*)d_out);
}